// Round 5
// baseline (312.120 us; speedup 1.0000x reference)
//
#include <hip/hip_runtime.h>
#include <stdint.h>

// GPT causal self-attention block. B=8, T=1024, C=768, H=8, D=96. f32 I/O.
// bf16 MFMA pipeline, fp32 accumulation. Causal mask input ignored.
// v3: barrier-free attention (K/V fragments loaded straight from global),
// Q pre-scaled by 1/sqrt(96)*log2(e) in the QKV epilogue (softmax uses exp2),
// P packed via v_cvt_pk_bf16_f32 with key-permuted layout matched by VT.

typedef unsigned short ushort_t;
typedef __attribute__((ext_vector_type(8))) short short8;     // 8 bf16 = 4 VGPRs
typedef __attribute__((ext_vector_type(4))) float floatx4;    // MFMA C/D frag
typedef __attribute__((ext_vector_type(4))) unsigned short ushort4v;

#define MFMA16(a, b, c) __builtin_amdgcn_mfma_f32_16x16x32_bf16(a, b, c, 0, 0, 0)
#define NEG_BIG (-1e30f)
#define QSCALE 0.14724444757f   // (1/sqrt(96)) * log2(e)

__device__ __forceinline__ unsigned short f2bf(float f) {
  union { float f; unsigned int u; } v; v.f = f;
  unsigned int r = (v.u + 0x7FFFu + ((v.u >> 16) & 1u)) >> 16;  // RNE
  return (unsigned short)r;
}
__device__ __forceinline__ float exp2_fast(float x) {
  float r;
  asm("v_exp_f32 %0, %1" : "=v"(r) : "v"(x));
  return r;
}
__device__ __forceinline__ unsigned int cvt_pk_bf16(float lo, float hi) {
  unsigned int r;
  asm("v_cvt_pk_bf16_f32 %0, %1, %2" : "=v"(r) : "v"(lo), "v"(hi));
  return r;
}

__global__ __launch_bounds__(256) void cvt_f32_bf16(
    const float* __restrict__ in, ushort_t* __restrict__ out, int n)
{
  int i = (blockIdx.x * 256 + threadIdx.x) * 4;
  if (i + 3 < n) {
    float4 v = *(const float4*)(in + i);
    ushort4v o;
    o.x = f2bf(v.x); o.y = f2bf(v.y); o.z = f2bf(v.z); o.w = f2bf(v.w);
    *(ushort4v*)(out + i) = o;
  } else {
    for (; i < n; ++i) out[i] = f2bf(in[i]);
  }
}

// ---------------------------------------------------------------------------
// QKV GEMM. q cols pre-scaled by QSCALE into QK; k cols raw into QK;
// v written TRANSPOSED into VT[b][h][d][T] with keys permuted inside each
// 64-group: key (t*16+l) -> pos (l*4+t). Attention's P uses the same order.
// ---------------------------------------------------------------------------
__global__ __launch_bounds__(256) void gemm_qkv(
    const ushort_t* __restrict__ A,   // 8192 x 768 bf16 (x)
    const ushort_t* __restrict__ W,   // 2304 x 768 bf16
    const float* __restrict__ bias,   // 2304 f32
    ushort_t* __restrict__ QK,        // 8192 x 1536 bf16
    ushort_t* __restrict__ VT)        // (64 bh) x 96 x 1024 bf16 (permuted)
{
  const int K = 768;
  __shared__ ushort_t As[128 * 32];
  __shared__ ushort_t Bs[128 * 32];

  const int tid  = threadIdx.x;
  const int lane = tid & 63;
  const int l15  = lane & 15;
  const int quad = lane >> 4;
  const int wid  = tid >> 6;
  const int m0 = blockIdx.x * 128;
  const int n0 = blockIdx.y * 128;
  const int wm = (wid >> 1) * 64;
  const int wn = (wid & 1) * 64;
  const int srow = tid >> 2;
  const int scol = (tid & 3) * 8;

  floatx4 acc[4][4] = {};

  const ushort_t* gA = A + (size_t)(m0 + srow) * K + scol;
  const ushort_t* gB = W + (size_t)(n0 + srow) * K + scol;
  ushort_t* lA = &As[wid * 512];
  ushort_t* lB = &Bs[wid * 512];

  for (int k0 = 0; k0 < K; k0 += 32) {
    __builtin_amdgcn_global_load_lds(
        (const __attribute__((address_space(1))) void*)gA,
        (__attribute__((address_space(3))) void*)lA, 16, 0, 0);
    __builtin_amdgcn_global_load_lds(
        (const __attribute__((address_space(1))) void*)(gA + (size_t)64 * K),
        (__attribute__((address_space(3))) void*)(lA + 64 * 32), 16, 0, 0);
    __builtin_amdgcn_global_load_lds(
        (const __attribute__((address_space(1))) void*)gB,
        (__attribute__((address_space(3))) void*)lB, 16, 0, 0);
    __builtin_amdgcn_global_load_lds(
        (const __attribute__((address_space(1))) void*)(gB + (size_t)64 * K),
        (__attribute__((address_space(3))) void*)(lB + 64 * 32), 16, 0, 0);
    gA += 32; gB += 32;
    __syncthreads();

    short8 af[4], bf[4];
#pragma unroll
    for (int t = 0; t < 4; ++t)
      af[t] = *(const short8*)&As[(wm + t * 16 + l15) * 32 + quad * 8];
#pragma unroll
    for (int t = 0; t < 4; ++t)
      bf[t] = *(const short8*)&Bs[(wn + t * 16 + l15) * 32 + quad * 8];
#pragma unroll
    for (int tm = 0; tm < 4; ++tm)
#pragma unroll
      for (int tn = 0; tn < 4; ++tn)
        acc[tm][tn] = MFMA16(af[tm], bf[tn], acc[tm][tn]);
    __syncthreads();
  }

#pragma unroll
  for (int tn = 0; tn < 4; ++tn) {
    const int gc = n0 + wn + tn * 16 + l15;
    const float bv = bias[gc];
    const bool isv = (gc >= 1536);          // whole 16-col tile same side
    const bool isq = (gc < 768);
    const int hh = (gc - 1536) / 96, dd = (gc - 1536) % 96;
#pragma unroll
    for (int tm = 0; tm < 4; ++tm) {
      const int gr = m0 + wm + tm * 16 + quad * 4;
#pragma unroll
      for (int r = 0; r < 4; ++r) {
        float val = acc[tm][tn][r] + bv;
        const int row = gr + r;
        if (!isv) {
          if (isq) val *= QSCALE;
          QK[(size_t)row * 1536 + gc] = f2bf(val);
        } else {
          const int bb = row >> 10, tt = row & 1023;
          const int pos = (tt & ~63) | (((tt & 15) << 2) | ((tt >> 4) & 3));
          VT[(((size_t)(bb * 8 + hh)) * 96 + dd) * 1024 + pos] = f2bf(val);
        }
      }
    }
  }
}

// ---------------------------------------------------------------------------
// Proj GEMM: C[m][n] = sum_k A[m][k] W[n][k] + bias[n], f32 out.
// ---------------------------------------------------------------------------
__global__ __launch_bounds__(256) void gemm_proj(
    const ushort_t* __restrict__ A,   // M x K bf16
    const ushort_t* __restrict__ W,   // N x K bf16
    const float* __restrict__ bias,   // N f32
    float* __restrict__ C,            // M x N f32
    int M, int N, int K)
{
  __shared__ ushort_t As[128 * 32];
  __shared__ ushort_t Bs[128 * 32];

  const int tid  = threadIdx.x;
  const int lane = tid & 63;
  const int l15  = lane & 15;
  const int quad = lane >> 4;
  const int wid  = tid >> 6;
  const int m0 = blockIdx.x * 128;
  const int n0 = blockIdx.y * 128;
  const int wm = (wid >> 1) * 64;
  const int wn = (wid & 1) * 64;
  const int srow = tid >> 2;
  const int scol = (tid & 3) * 8;

  floatx4 acc[4][4] = {};

  const ushort_t* gA = A + (size_t)(m0 + srow) * K + scol;
  const ushort_t* gB = W + (size_t)(n0 + srow) * K + scol;
  ushort_t* lA = &As[wid * 512];
  ushort_t* lB = &Bs[wid * 512];

  for (int k0 = 0; k0 < K; k0 += 32) {
    __builtin_amdgcn_global_load_lds(
        (const __attribute__((address_space(1))) void*)gA,
        (__attribute__((address_space(3))) void*)lA, 16, 0, 0);
    __builtin_amdgcn_global_load_lds(
        (const __attribute__((address_space(1))) void*)(gA + (size_t)64 * K),
        (__attribute__((address_space(3))) void*)(lA + 64 * 32), 16, 0, 0);
    __builtin_amdgcn_global_load_lds(
        (const __attribute__((address_space(1))) void*)gB,
        (__attribute__((address_space(3))) void*)lB, 16, 0, 0);
    __builtin_amdgcn_global_load_lds(
        (const __attribute__((address_space(1))) void*)(gB + (size_t)64 * K),
        (__attribute__((address_space(3))) void*)(lB + 64 * 32), 16, 0, 0);
    gA += 32; gB += 32;
    __syncthreads();

    short8 af[4], bf[4];
#pragma unroll
    for (int t = 0; t < 4; ++t)
      af[t] = *(const short8*)&As[(wm + t * 16 + l15) * 32 + quad * 8];
#pragma unroll
    for (int t = 0; t < 4; ++t)
      bf[t] = *(const short8*)&Bs[(wn + t * 16 + l15) * 32 + quad * 8];
#pragma unroll
    for (int tm = 0; tm < 4; ++tm)
#pragma unroll
      for (int tn = 0; tn < 4; ++tn)
        acc[tm][tn] = MFMA16(af[tm], bf[tn], acc[tm][tn]);
    __syncthreads();
  }

#pragma unroll
  for (int tn = 0; tn < 4; ++tn) {
    const int gc = n0 + wn + tn * 16 + l15;
    const float bv = bias[gc];
#pragma unroll
    for (int tm = 0; tm < 4; ++tm) {
      const int gr = m0 + wm + tm * 16 + quad * 4;
#pragma unroll
      for (int r = 0; r < 4; ++r)
        C[(size_t)(gr + r) * N + gc] = acc[tm][tn][r] + bv;
    }
  }
}

// ---------------------------------------------------------------------------
// Fused causal flash attention v3 — BARRIER-FREE.
// Grid (8, 64): block = (b,h); wave w owns one 32-row q-chunk:
//   w<2 -> chunk 2*bx+w ; w>=2 -> chunk 31-(2*bx+w-2)   (balanced pairing)
// Each wave: 2 q-tiles (16 rows). K/V fragments loaded directly from global
// (no LDS staging, no __syncthreads). Only LDS use: per-wave P round-trip.
// Q is pre-scaled (QSCALE) so softmax works in the exp2 domain.
// VT keys are permuted (pos l*4+t <-> key t*16+l) to match packed P stores.
// ---------------------------------------------------------------------------
__global__ __launch_bounds__(256) void attn_fused(
    const ushort_t* __restrict__ QK,   // (B*T) x 1536 bf16  [q_scaled|k]
    const ushort_t* __restrict__ VT,   // (64 bh) x 96 x 1024 bf16 (permuted)
    ushort_t* __restrict__ y)          // (B*T) x 768 bf16
{
  __shared__ ushort_t Ps[4][16 * 80];  // per-wave P, row stride 80 (16B-align)

  const int tid  = threadIdx.x;
  const int lane = tid & 63;
  const int l15  = lane & 15;
  const int quad = lane >> 4;
  const int wid  = tid >> 6;
  const int bh = blockIdx.y;
  const int b = bh >> 3;
  const int h = bh & 7;
  const int qoff = h * 96;

  const int cc = (wid < 2) ? (blockIdx.x * 2 + wid)
                           : (31 - (blockIdx.x * 2 + (wid - 2)));
  const int q0 = cc * 32;                      // wave owns rows q0..q0+31
  const size_t rowbase = (size_t)b * 1024;
  const ushort_t* kb  = QK + (rowbase * 1536) + 768 + qoff;   // key rows
  const ushort_t* vtb = VT + (size_t)bh * 96 * 1024;

  // Q fragments (A layout) for both q-tiles, K=96 in 3 chunks of 32
  short8 qf[2][3];
#pragma unroll
  for (int qt = 0; qt < 2; ++qt)
#pragma unroll
    for (int c = 0; c < 3; ++c)
      qf[qt][c] = *(const short8*)(QK + (rowbase + q0 + qt * 16 + l15) * 1536 +
                                   qoff + c * 32 + quad * 8);

  float m_i[2][4], l_i[2][4];
  floatx4 O[2][6] = {};
#pragma unroll
  for (int qt = 0; qt < 2; ++qt)
#pragma unroll
    for (int j = 0; j < 4; ++j) { m_i[qt][j] = NEG_BIG; l_i[qt][j] = 0.f; }

  for (int k0 = 0; k0 <= q0; k0 += 64) {
    // ---- QK^T: 2 q-tiles x 64 keys; each K fragment used twice
    floatx4 s[2][4] = {};
#pragma unroll
    for (int t = 0; t < 4; ++t)
#pragma unroll
      for (int c = 0; c < 3; ++c) {
        short8 kf = *(const short8*)(kb + (size_t)(k0 + t * 16 + l15) * 1536 +
                                     c * 32 + quad * 8);
        s[0][t] = MFMA16(qf[0][c], kf, s[0][t]);
        s[1][t] = MFMA16(qf[1][c], kf, s[1][t]);
      }

#pragma unroll
    for (int qt = 0; qt < 2; ++qt) {
      const int qbase = q0 + qt * 16;
      const bool full = (k0 + 63 <= qbase);    // wave-uniform: no masking
      // ---- online softmax (exp2 domain), 4 rows/lane
#pragma unroll
      for (int j = 0; j < 4; ++j) {
        const int rq = qbase + quad * 4 + j;
        float sv[4];
        if (full) {
#pragma unroll
          for (int t = 0; t < 4; ++t) sv[t] = s[qt][t][j];
        } else {
#pragma unroll
          for (int t = 0; t < 4; ++t)
            sv[t] = (k0 + t * 16 + l15 <= rq) ? s[qt][t][j] : NEG_BIG;
        }
        float mt = fmaxf(fmaxf(sv[0], sv[1]), fmaxf(sv[2], sv[3]));
        mt = fmaxf(mt, __shfl_xor(mt, 1));
        mt = fmaxf(mt, __shfl_xor(mt, 2));
        mt = fmaxf(mt, __shfl_xor(mt, 4));
        mt = fmaxf(mt, __shfl_xor(mt, 8));
        const float mn = fmaxf(m_i[qt][j], mt);
        const float al = exp2_fast(m_i[qt][j] - mn);
        float p[4];
#pragma unroll
        for (int t = 0; t < 4; ++t) p[t] = exp2_fast(sv[t] - mn);
        // packed store, permuted: key t*16+l15 -> pos l15*4+t
        const unsigned int d0 = cvt_pk_bf16(p[0], p[1]);
        const unsigned int d1 = cvt_pk_bf16(p[2], p[3]);
        *(uint2*)&Ps[wid][(quad * 4 + j) * 80 + l15 * 4] = make_uint2(d0, d1);
        float rs = (p[0] + p[1]) + (p[2] + p[3]);
        rs += __shfl_xor(rs, 1);
        rs += __shfl_xor(rs, 2);
        rs += __shfl_xor(rs, 4);
        rs += __shfl_xor(rs, 8);
        l_i[qt][j] = l_i[qt][j] * al + rs;
        m_i[qt][j] = mn;
#pragma unroll
        for (int f = 0; f < 6; ++f) O[qt][f][j] *= al;
      }
      asm volatile("s_waitcnt lgkmcnt(0)" ::: "memory");  // in-wave P w->r
      short8 pf[2];
#pragma unroll
      for (int u = 0; u < 2; ++u)
        pf[u] = *(const short8*)&Ps[wid][l15 * 80 + u * 32 + quad * 8];
      // ---- P·V, V fragments straight from (permuted) global VT
#pragma unroll
      for (int u = 0; u < 2; ++u)
#pragma unroll
        for (int f = 0; f < 6; ++f) {
          short8 vf = *(const short8*)(vtb + (size_t)(f * 16 + l15) * 1024 +
                                       k0 + u * 32 + quad * 8);
          O[qt][f] = MFMA16(pf[u], vf, O[qt][f]);
        }
    }
  }

#pragma unroll
  for (int qt = 0; qt < 2; ++qt)
#pragma unroll
    for (int j = 0; j < 4; ++j) {
      const float inv = 1.0f / fmaxf(l_i[qt][j], 1e-20f);
      const size_t row = rowbase + q0 + qt * 16 + quad * 4 + j;
#pragma unroll
      for (int f = 0; f < 6; ++f)
        y[row * 768 + qoff + f * 16 + l15] = f2bf(O[qt][f][j] * inv);
    }
}

// ---------------------------------------------------------------------------
extern "C" void kernel_launch(void* const* d_in, const int* in_sizes, int n_in,
                              void* d_out, int out_size, void* d_ws, size_t ws_size,
                              hipStream_t stream)
{
  const float* x_f  = (const float*)d_in[0];
  const float* wa_f = (const float*)d_in[1];
  const float* ba_f = (const float*)d_in[2];
  const float* wp_f = (const float*)d_in[3];
  const float* bp_f = (const float*)d_in[4];
  float* out = (float*)d_out;

  ushort_t* xb  = (ushort_t*)d_ws;                    // 8192 x  768
  ushort_t* wab = xb  + (size_t)8192 * 768;           // 2304 x  768
  ushort_t* wpb = wab + (size_t)2304 * 768;           //  768 x  768
  ushort_t* QK  = wpb + (size_t)768 * 768;            // 8192 x 1536
  ushort_t* VT  = QK  + (size_t)8192 * 1536;          // 64 x 96 x 1024
  ushort_t* yw  = VT  + (size_t)8192 * 768;           // 8192 x  768

  const int nx = 8192 * 768, nwa = 2304 * 768, nwp = 768 * 768;
  cvt_f32_bf16<<<(nx  / 4 + 255) / 256, 256, 0, stream>>>(x_f,  xb,  nx);
  cvt_f32_bf16<<<(nwa / 4 + 255) / 256, 256, 0, stream>>>(wa_f, wab, nwa);
  cvt_f32_bf16<<<(nwp / 4 + 255) / 256, 256, 0, stream>>>(wp_f, wpb, nwp);

  gemm_qkv<<<dim3(64, 18), 256, 0, stream>>>(xb, wab, ba_f, QK, VT);
  attn_fused<<<dim3(8, 64), 256, 0, stream>>>(QK, VT, yw);
  gemm_proj<<<dim3(64, 6), 256, 0, stream>>>(yw, wpb, bp_f, out,
                                             8192, 768, 768);
}

// Round 9
// 261.541 us; speedup vs baseline: 1.1934x; 1.1934x over previous
//
#include <hip/hip_runtime.h>
#include <stdint.h>

// GPT causal self-attention block. B=8, T=1024, C=768, H=8, D=96. f32 I/O.
// bf16 MFMA pipeline, fp32 accumulation. Causal mask input ignored.
// v6: r4's PROVEN two-barrier single-buffered attention (stage->sync->
// compute->sync) + r5-proven QSCALE/exp2 softmax. The single-barrier dbuf
// prefetch loop (r6/r7/r8) is abandoned: r8 showed it races (passed first
// launch, diverged across graph replays). Only other change vs r4: gemm_qkv
// VT epilogue packs the 4-row quad into one 8B store.

typedef unsigned short ushort_t;
typedef __attribute__((ext_vector_type(8))) short short8;     // 8 bf16 = 4 VGPRs
typedef __attribute__((ext_vector_type(4))) float floatx4;    // MFMA C/D frag
typedef __attribute__((ext_vector_type(4))) unsigned short ushort4v;

#define MFMA16(a, b, c) __builtin_amdgcn_mfma_f32_16x16x32_bf16(a, b, c, 0, 0, 0)
#define NEG_BIG (-1e30f)
#define QSCALE 0.14724444757f   // (1/sqrt(96)) * log2(e)
#define AS1 __attribute__((address_space(1)))
#define AS3 __attribute__((address_space(3)))

__device__ __forceinline__ unsigned short f2bf(float f) {
  union { float f; unsigned int u; } v; v.f = f;
  unsigned int r = (v.u + 0x7FFFu + ((v.u >> 16) & 1u)) >> 16;  // RNE
  return (unsigned short)r;
}
__device__ __forceinline__ float exp2_fast(float x) {
  float r;
  asm("v_exp_f32 %0, %1" : "=v"(r) : "v"(x));
  return r;
}

__global__ __launch_bounds__(256) void cvt_f32_bf16(
    const float* __restrict__ in, ushort_t* __restrict__ out, int n)
{
  int i = (blockIdx.x * 256 + threadIdx.x) * 4;
  if (i + 3 < n) {
    float4 v = *(const float4*)(in + i);
    ushort4v o;
    o.x = f2bf(v.x); o.y = f2bf(v.y); o.z = f2bf(v.z); o.w = f2bf(v.w);
    *(ushort4v*)(out + i) = o;
  } else {
    for (; i < n; ++i) out[i] = f2bf(in[i]);
  }
}

// ---------------------------------------------------------------------------
// QKV GEMM. q cols pre-scaled by QSCALE into QK; k raw into QK; v written
// TRANSPOSED into VT[b][h][d][T]; 4-row quad packed into one 8B store.
// ---------------------------------------------------------------------------
__global__ __launch_bounds__(256) void gemm_qkv(
    const ushort_t* __restrict__ A,   // 8192 x 768 bf16 (x)
    const ushort_t* __restrict__ W,   // 2304 x 768 bf16
    const float* __restrict__ bias,   // 2304 f32
    ushort_t* __restrict__ QK,        // 8192 x 1536 bf16
    ushort_t* __restrict__ VT)        // (64 bh) x 96 x 1024 bf16
{
  const int K = 768;
  __shared__ ushort_t As[128 * 32];
  __shared__ ushort_t Bs[128 * 32];

  const int tid  = threadIdx.x;
  const int lane = tid & 63;
  const int l15  = lane & 15;
  const int quad = lane >> 4;
  const int wid  = tid >> 6;
  const int m0 = blockIdx.x * 128;
  const int n0 = blockIdx.y * 128;
  const int wm = (wid >> 1) * 64;
  const int wn = (wid & 1) * 64;
  const int srow = tid >> 2;
  const int scol = (tid & 3) * 8;

  floatx4 acc[4][4] = {};

  const ushort_t* gA = A + (size_t)(m0 + srow) * K + scol;
  const ushort_t* gB = W + (size_t)(n0 + srow) * K + scol;
  ushort_t* lA = &As[wid * 512];
  ushort_t* lB = &Bs[wid * 512];

  for (int k0 = 0; k0 < K; k0 += 32) {
    __builtin_amdgcn_global_load_lds((const AS1 void*)gA, (AS3 void*)lA, 16, 0, 0);
    __builtin_amdgcn_global_load_lds((const AS1 void*)(gA + (size_t)64 * K),
                                     (AS3 void*)(lA + 64 * 32), 16, 0, 0);
    __builtin_amdgcn_global_load_lds((const AS1 void*)gB, (AS3 void*)lB, 16, 0, 0);
    __builtin_amdgcn_global_load_lds((const AS1 void*)(gB + (size_t)64 * K),
                                     (AS3 void*)(lB + 64 * 32), 16, 0, 0);
    gA += 32; gB += 32;
    __syncthreads();

    short8 af[4], bf[4];
#pragma unroll
    for (int t = 0; t < 4; ++t)
      af[t] = *(const short8*)&As[(wm + t * 16 + l15) * 32 + quad * 8];
#pragma unroll
    for (int t = 0; t < 4; ++t)
      bf[t] = *(const short8*)&Bs[(wn + t * 16 + l15) * 32 + quad * 8];
#pragma unroll
    for (int tm = 0; tm < 4; ++tm)
#pragma unroll
      for (int tn = 0; tn < 4; ++tn)
        acc[tm][tn] = MFMA16(af[tm], bf[tn], acc[tm][tn]);
    __syncthreads();
  }

#pragma unroll
  for (int tn = 0; tn < 4; ++tn) {
    const int gc = n0 + wn + tn * 16 + l15;
    const float bv = bias[gc];
    const bool isv = (gc >= 1536);
    const bool isq = (gc < 768);
    const int hh = (gc - 1536) / 96, dd = (gc - 1536) % 96;
#pragma unroll
    for (int tm = 0; tm < 4; ++tm) {
      const int gr = m0 + wm + tm * 16 + quad * 4;
      if (!isv) {
#pragma unroll
        for (int r = 0; r < 4; ++r) {
          float val = acc[tm][tn][r] + bv;
          if (isq) val *= QSCALE;
          QK[(size_t)(gr + r) * 1536 + gc] = f2bf(val);
        }
      } else {
        ushort4v vv;
#pragma unroll
        for (int r = 0; r < 4; ++r) vv[r] = f2bf(acc[tm][tn][r] + bv);
        const int bb = gr >> 10, tt = gr & 1023;   // 4 consecutive tt, 8B-aligned
        *(ushort4v*)&VT[(((size_t)(bb * 8 + hh)) * 96 + dd) * 1024 + tt] = vv;
      }
    }
  }
}

// ---------------------------------------------------------------------------
// Proj GEMM: C[m][n] = sum_k A[m][k] W[n][k] + bias[n], f32 out.
// ---------------------------------------------------------------------------
__global__ __launch_bounds__(256) void gemm_proj(
    const ushort_t* __restrict__ A, const ushort_t* __restrict__ W,
    const float* __restrict__ bias, float* __restrict__ C,
    int M, int N, int K)
{
  __shared__ ushort_t As[128 * 32];
  __shared__ ushort_t Bs[128 * 32];

  const int tid  = threadIdx.x;
  const int lane = tid & 63;
  const int l15  = lane & 15;
  const int quad = lane >> 4;
  const int wid  = tid >> 6;
  const int m0 = blockIdx.x * 128;
  const int n0 = blockIdx.y * 128;
  const int wm = (wid >> 1) * 64;
  const int wn = (wid & 1) * 64;
  const int srow = tid >> 2;
  const int scol = (tid & 3) * 8;

  floatx4 acc[4][4] = {};

  const ushort_t* gA = A + (size_t)(m0 + srow) * K + scol;
  const ushort_t* gB = W + (size_t)(n0 + srow) * K + scol;
  ushort_t* lA = &As[wid * 512];
  ushort_t* lB = &Bs[wid * 512];

  for (int k0 = 0; k0 < K; k0 += 32) {
    __builtin_amdgcn_global_load_lds((const AS1 void*)gA, (AS3 void*)lA, 16, 0, 0);
    __builtin_amdgcn_global_load_lds((const AS1 void*)(gA + (size_t)64 * K),
                                     (AS3 void*)(lA + 64 * 32), 16, 0, 0);
    __builtin_amdgcn_global_load_lds((const AS1 void*)gB, (AS3 void*)lB, 16, 0, 0);
    __builtin_amdgcn_global_load_lds((const AS1 void*)(gB + (size_t)64 * K),
                                     (AS3 void*)(lB + 64 * 32), 16, 0, 0);
    gA += 32; gB += 32;
    __syncthreads();

    short8 af[4], bf[4];
#pragma unroll
    for (int t = 0; t < 4; ++t)
      af[t] = *(const short8*)&As[(wm + t * 16 + l15) * 32 + quad * 8];
#pragma unroll
    for (int t = 0; t < 4; ++t)
      bf[t] = *(const short8*)&Bs[(wn + t * 16 + l15) * 32 + quad * 8];
#pragma unroll
    for (int tm = 0; tm < 4; ++tm)
#pragma unroll
      for (int tn = 0; tn < 4; ++tn)
        acc[tm][tn] = MFMA16(af[tm], bf[tn], acc[tm][tn]);
    __syncthreads();
  }

#pragma unroll
  for (int tn = 0; tn < 4; ++tn) {
    const int gc = n0 + wn + tn * 16 + l15;
    const float bv = bias[gc];
#pragma unroll
    for (int tm = 0; tm < 4; ++tm) {
      const int gr = m0 + wm + tm * 16 + quad * 4;
#pragma unroll
      for (int r = 0; r < 4; ++r)
        C[(size_t)(gr + r) * N + gc] = acc[tm][tn][r] + bv;
    }
  }
}

// ---------------------------------------------------------------------------
// Fused causal flash attention v6 = r4's two-barrier structure + exp2 softmax.
// Grid (16, 64): block = (b,h) + paired q-chunks cA=bx, cB=31-cA (32 rows ea).
// Waves 0,1 -> chunk A; waves 2,3 -> chunk B (16 q-rows per wave).
// Per 64-key tile: stage (Ks via global_load_lds, Vt via padded LDS rows);
// __syncthreads; gated compute; __syncthreads.
// ---------------------------------------------------------------------------
__global__ __launch_bounds__(256) void attn_fused(
    const ushort_t* __restrict__ QK,   // (B*T) x 1536 bf16  [q_scaled|k]
    const ushort_t* __restrict__ VT,   // (64 bh) x 96 x 1024 bf16
    ushort_t* __restrict__ y)          // (B*T) x 768 bf16
{
  __shared__ ushort_t Ks[64 * 96];     // natural [key][d]
  __shared__ ushort_t Vt[96 * 72];     // padded rows for b128 reads
  __shared__ ushort_t Ps[4][16 * 72];  // per-wave P round-trip

  const int tid  = threadIdx.x;
  const int lane = tid & 63;
  const int l15  = lane & 15;
  const int quad = lane >> 4;
  const int wid  = tid >> 6;
  const int bh = blockIdx.y;
  const int b = bh >> 3;
  const int h = bh & 7;
  const int qoff = h * 96;

  const int cA = blockIdx.x;           // 0..15
  const int cB = 31 - cA;              // 16..31
  const int myChunk = (wid < 2) ? cA : cB;
  const int q0 = myChunk * 32 + (wid & 1) * 16;   // wave's first q row
  const int kend = cB * 32 + 32;

  const size_t rowbase = (size_t)b * 1024;
  const ushort_t* kb  = QK + rowbase * 1536 + 768 + qoff;
  const ushort_t* vtb = VT + (size_t)bh * 96 * 1024;

  // Q fragments (A layout), K=96 in 3 chunks of 32 (q pre-scaled by QSCALE)
  short8 qf[3];
#pragma unroll
  for (int c = 0; c < 3; ++c)
    qf[c] = *(const short8*)(QK + (rowbase + q0 + l15) * 1536 + qoff +
                             c * 32 + quad * 8);

  float m_i[4] = {NEG_BIG, NEG_BIG, NEG_BIG, NEG_BIG};
  float l_i[4] = {0.f, 0.f, 0.f, 0.f};
  floatx4 O[6] = {};

  for (int k0 = 0; k0 < kend; k0 += 64) {
    // --- stage K tile [64][96] via global_load_lds (wave w -> rows w*16..+16)
#pragma unroll
    for (int i = 0; i < 3; ++i) {
      const int e = wid * 1536 + i * 512 + lane * 8;
      const int kr = e / 96, kc = e % 96;
      __builtin_amdgcn_global_load_lds(
          (const AS1 void*)(kb + (size_t)(k0 + kr) * 1536 + kc),
          (AS3 void*)(&Ks[wid * 1536 + i * 512]), 16, 0, 0);
    }
    // --- stage V^T tile [96][64] -> padded LDS rows of 72
#pragma unroll
    for (int g = 0; g < 3; ++g) {
      const int d = g * 32 + (tid >> 3);
      const int kc = (tid & 7) * 8;
      short8 v = *(const short8*)(vtb + (size_t)d * 1024 + k0 + kc);
      *(short8*)&Vt[d * 72 + kc] = v;
    }
    __syncthreads();

    if (k0 < q0 + 16) {                // wave-uniform activity gate
      floatx4 s[4] = {};
#pragma unroll
      for (int t = 0; t < 4; ++t)
#pragma unroll
        for (int c = 0; c < 3; ++c) {
          short8 kf = *(const short8*)&Ks[(t * 16 + l15) * 96 + c * 32 +
                                          quad * 8];
          s[t] = MFMA16(qf[c], kf, s[t]);
        }
      const bool full = (k0 + 63 <= q0);
#pragma unroll
      for (int j = 0; j < 4; ++j) {
        const int rq = q0 + quad * 4 + j;
        float sv[4];
        if (full) {
#pragma unroll
          for (int t = 0; t < 4; ++t) sv[t] = s[t][j];
        } else {
#pragma unroll
          for (int t = 0; t < 4; ++t)
            sv[t] = (k0 + t * 16 + l15 <= rq) ? s[t][j] : NEG_BIG;
        }
        float mt = fmaxf(fmaxf(sv[0], sv[1]), fmaxf(sv[2], sv[3]));
        mt = fmaxf(mt, __shfl_xor(mt, 1));
        mt = fmaxf(mt, __shfl_xor(mt, 2));
        mt = fmaxf(mt, __shfl_xor(mt, 4));
        mt = fmaxf(mt, __shfl_xor(mt, 8));
        const float mn = fmaxf(m_i[j], mt);
        const float al = exp2_fast(m_i[j] - mn);
        float rs = 0.f;
#pragma unroll
        for (int t = 0; t < 4; ++t) {
          const float p = exp2_fast(sv[t] - mn);
          rs += p;
          Ps[wid][(quad * 4 + j) * 72 + t * 16 + l15] = f2bf(p);
        }
        rs += __shfl_xor(rs, 1);
        rs += __shfl_xor(rs, 2);
        rs += __shfl_xor(rs, 4);
        rs += __shfl_xor(rs, 8);
        l_i[j] = l_i[j] * al + rs;
        m_i[j] = mn;
#pragma unroll
        for (int f = 0; f < 6; ++f) O[f][j] *= al;
      }
      asm volatile("s_waitcnt lgkmcnt(0)" ::: "memory");  // in-wave P w->r
      short8 pf[2];
#pragma unroll
      for (int u = 0; u < 2; ++u)
        pf[u] = *(const short8*)&Ps[wid][l15 * 72 + u * 32 + quad * 8];
#pragma unroll
      for (int u = 0; u < 2; ++u)
#pragma unroll
        for (int f = 0; f < 6; ++f) {
          short8 vf = *(const short8*)&Vt[(f * 16 + l15) * 72 + u * 32 +
                                          quad * 8];
          O[f] = MFMA16(pf[u], vf, O[f]);
        }
    }
    __syncthreads();
  }

#pragma unroll
  for (int j = 0; j < 4; ++j) {
    const float inv = 1.0f / fmaxf(l_i[j], 1e-20f);
    const size_t row = rowbase + q0 + quad * 4 + j;
#pragma unroll
    for (int f = 0; f < 6; ++f)
      y[row * 768 + qoff + f * 16 + l15] = f2bf(O[f][j] * inv);
  }
}

// ---------------------------------------------------------------------------
extern "C" void kernel_launch(void* const* d_in, const int* in_sizes, int n_in,
                              void* d_out, int out_size, void* d_ws, size_t ws_size,
                              hipStream_t stream)
{
  const float* x_f  = (const float*)d_in[0];
  const float* wa_f = (const float*)d_in[1];
  const float* ba_f = (const float*)d_in[2];
  const float* wp_f = (const float*)d_in[3];
  const float* bp_f = (const float*)d_in[4];
  float* out = (float*)d_out;

  ushort_t* xb  = (ushort_t*)d_ws;                    // 8192 x  768
  ushort_t* wab = xb  + (size_t)8192 * 768;           // 2304 x  768
  ushort_t* wpb = wab + (size_t)2304 * 768;           //  768 x  768
  ushort_t* QK  = wpb + (size_t)768 * 768;            // 8192 x 1536
  ushort_t* VT  = QK  + (size_t)8192 * 1536;          // 64 x 96 x 1024
  ushort_t* yw  = VT  + (size_t)8192 * 768;           // 8192 x  768

  const int nx = 8192 * 768, nwa = 2304 * 768, nwp = 768 * 768;
  cvt_f32_bf16<<<(nx  / 4 + 255) / 256, 256, 0, stream>>>(x_f,  xb,  nx);
  cvt_f32_bf16<<<(nwa / 4 + 255) / 256, 256, 0, stream>>>(wa_f, wab, nwa);
  cvt_f32_bf16<<<(nwp / 4 + 255) / 256, 256, 0, stream>>>(wp_f, wpb, nwp);

  gemm_qkv<<<dim3(64, 18), 256, 0, stream>>>(xb, wab, ba_f, QK, VT);
  attn_fused<<<dim3(16, 64), 256, 0, stream>>>(QK, VT, yw);
  gemm_proj<<<dim3(64, 6), 256, 0, stream>>>(yw, wpb, bp_f, out,
                                             8192, 768, 768);
}